// Round 3
// baseline (641.928 us; speedup 1.0000x reference)
//
#include <hip/hip_runtime.h>
#include <math.h>

// ---- types ----------------------------------------------------------------
typedef __attribute__((ext_vector_type(8))) __bf16 bf16x8;   // MFMA A/B frag (4 VGPR)
typedef __attribute__((ext_vector_type(8))) short  short8;   // raw 16B store
typedef __attribute__((ext_vector_type(4))) unsigned short ushort4v;
typedef __attribute__((ext_vector_type(4))) float  floatx4;  // MFMA C/D frag

typedef __attribute__((address_space(1))) unsigned int as1_u32;
typedef __attribute__((address_space(3))) unsigned int as3_u32;

// async global->LDS, 16B per lane; LDS dest = wave-uniform base + lane*16B
__device__ __forceinline__ void async_copy16(const void* g, void* l) {
  __builtin_amdgcn_global_load_lds((const as1_u32*)g, (as3_u32*)l, 16, 0, 0);
}

__device__ __forceinline__ unsigned short f2bf(float f) {  // RNE float->bf16 bits
  union { float f; unsigned u; } v; v.f = f;
  unsigned r = v.u + 0x7fffu + ((v.u >> 16) & 1u);
  return (unsigned short)(r >> 16);
}

__device__ __forceinline__ floatx4 mfma_bf16(bf16x8 a, bf16x8 b, floatx4 c) {
  return __builtin_amdgcn_mfma_f32_16x16x32_bf16(a, b, c, 0, 0, 0);
}

__device__ __forceinline__ bf16x8 lds_frag(const unsigned short* p) {
  return *(const bf16x8*)(const void*)p;  // ds_read_b128, 16B aligned by construction
}

// ---- f32 -> bf16 convert (RNE), vectorized 4/thread -----------------------
__global__ __launch_bounds__(256)
void cvt_f32_bf16(const float* __restrict__ src, unsigned short* __restrict__ dst, int n4) {
  const int i = blockIdx.x * 256 + threadIdx.x;
  if (i < n4) {
    const float4 v = ((const float4*)src)[i];
    ushort4v o;
    o.x = f2bf(v.x); o.y = f2bf(v.y); o.z = f2bf(v.z); o.w = f2bf(v.w);
    *(ushort4v*)(void*)(dst + (size_t)i * 4) = o;
  }
}

// ---- C = A(MxK) * B(NxK)^T, K=512, bf16 in/out, fp32 accumulate -----------
// m97-verified structure: 128x128 tile, BK=64, global_load_lds w=16, 4 waves.
__global__ __launch_bounds__(256, 2)
void gemm_bt(const unsigned short* __restrict__ A,
             const unsigned short* __restrict__ B,
             unsigned short* __restrict__ C, int M, int N) {
  __shared__ unsigned short As[128 * 64];
  __shared__ unsigned short Bs[128 * 64];
  const int tid = threadIdx.x;
  const int w = tid >> 6, lane = tid & 63;
  const int quad = lane >> 4, l15 = lane & 15;
  const int wm = w >> 1, wn = w & 1;
  const int m0 = blockIdx.x * 128, n0 = blockIdx.y * 128;
  const int lr = lane >> 3, lc = (lane & 7) * 8;  // 8 rows x 64 cols per copy unit

  floatx4 acc[16];
#pragma unroll
  for (int i = 0; i < 16; i++) acc[i] = (floatx4){0.f, 0.f, 0.f, 0.f};

  for (int kt = 0; kt < 8; kt++) {
    __syncthreads();  // prev tile's ds_reads drained before overwrite
#pragma unroll
    for (int i = 0; i < 4; i++) {
      const int c = w * 4 + i;
      const int row = c * 8 + lr;
      async_copy16(A + (size_t)(m0 + row) * 512 + kt * 64 + lc, &As[c * 512]);
      async_copy16(B + (size_t)(n0 + row) * 512 + kt * 64 + lc, &Bs[c * 512]);
    }
    __syncthreads();  // s_waitcnt vmcnt(0) before s_barrier -> LDS ready
#pragma unroll
    for (int kc = 0; kc < 2; kc++) {
      bf16x8 af[4], bfv[4];
#pragma unroll
      for (int i = 0; i < 4; i++) {
        af[i]  = lds_frag(&As[(wm * 64 + i * 16 + l15) * 64 + kc * 32 + quad * 8]);
        bfv[i] = lds_frag(&Bs[(wn * 64 + i * 16 + l15) * 64 + kc * 32 + quad * 8]);
      }
#pragma unroll
      for (int mi = 0; mi < 4; mi++)
#pragma unroll
        for (int ni = 0; ni < 4; ni++)
          acc[mi * 4 + ni] = mfma_bf16(af[mi], bfv[ni], acc[mi * 4 + ni]);
    }
  }
  // C/D layout: col = lane&15, row = quad*4 + r (m89-verified)
#pragma unroll
  for (int mi = 0; mi < 4; mi++)
#pragma unroll
    for (int ni = 0; ni < 4; ni++)
#pragma unroll
      for (int r = 0; r < 4; r++) {
        const int row = m0 + wm * 64 + mi * 16 + quad * 4 + r;
        const int col = n0 + wn * 64 + ni * 16 + l15;
        C[(size_t)row * N + col] = f2bf(acc[mi * 4 + ni][r]);
      }
}

// ---- fused attention: full (non-causal) softmax over 4096 keys ------------
// CONSERVATIVE staging: single-buffer, issue-copies -> barrier -> read.
// Block: 32 q-rows. 4 waves: wq in {0,1} (16 q-rows), wd in {0,1}.
#define SCALE 0.044194173824159216f  // 1/sqrt(512)

__global__ __launch_bounds__(256, 2)
void attn_kernel(const unsigned short* __restrict__ Qg,
                 const unsigned short* __restrict__ Kg,
                 const unsigned short* __restrict__ Vt,   // [512][16384] = V^T
                 float* __restrict__ O) {                 // f32 output
  __shared__ unsigned short Ks[64 * 128];   // 16 KB: 64 keys x 128 feats
  __shared__ unsigned short Vs[256 * 64];   // 32 KB: 256 d   x 64 keys
  __shared__ float Sx[32][64];              // 8 KB score exchange
  __shared__ unsigned short Pb[32 * 80];    // 5 KB P (stride 80 -> aligned b128)
  __shared__ float m_row[32], l_row[32], a_row[32];

  const int tid = threadIdx.x;
  const int w = tid >> 6, lane = tid & 63;
  const int quad = lane >> 4, l15 = lane & 15;
  const int wq = w >> 1, wd = w & 1;

  // XCD swizzle: batch b = bits[2:1] of linear id -> batch K/V pinned per XCD pair
  const int g = blockIdx.x;
  const int b = (g >> 1) & 3;
  const int qt = ((g >> 3) << 1) | (g & 1);
  const int q0 = qt * 32;

  if (tid < 32) { m_row[tid] = -3.0e38f; l_row[tid] = 0.f; }

  // Q A-fragments in registers: A[m=l15][k = i*32 + quad*8 + j]
  bf16x8 qf[16];
  {
    const unsigned short* qrow = Qg + (size_t)(b * 4096 + q0 + wq * 16 + l15) * 512;
#pragma unroll
    for (int i = 0; i < 16; i++)
      qf[i] = *(const bf16x8*)(const void*)(qrow + i * 32 + quad * 8);
  }

  floatx4 oacc[16];
#pragma unroll
  for (int i = 0; i < 16; i++) oacc[i] = (floatx4){0.f, 0.f, 0.f, 0.f};

  const int srow = tid >> 3, sg = tid & 7;   // softmax: 8 threads per q-row
  const int k_key = lane >> 4, k_f = (lane & 15) * 8;  // K-copy unit: 4 keys x 128 f
  const int v_d = lane >> 3, v_k = (lane & 7) * 8;     // V-copy unit: 8 d x 64 keys

  for (int kt = 0; kt < 64; kt++) {
    const unsigned short* kbase = Kg + (size_t)(b * 4096 + kt * 64) * 512;

    // ---- phase 1: S(32q x 64keys) = Q K^T, 4 feature mega-chunks of 128
    floatx4 sacc[2];
    sacc[0] = (floatx4){0.f, 0.f, 0.f, 0.f};
    sacc[1] = (floatx4){0.f, 0.f, 0.f, 0.f};
#pragma unroll
    for (int kk2 = 0; kk2 < 4; kk2++) {
      __syncthreads();  // Ks free (prev reads drained at this barrier)
#pragma unroll
      for (int u = 0; u < 4; u++) {
        const int unit = w * 4 + u;  // 0..15, each 4 keys x 128 feats
        async_copy16(kbase + (size_t)(unit * 4 + k_key) * 512 + kk2 * 128 + k_f,
                     &Ks[unit * 512]);
      }
      __syncthreads();  // vmcnt(0) drained -> Ks ready
#pragma unroll
      for (int kc = 0; kc < 4; kc++)
#pragma unroll
        for (int s = 0; s < 2; s++) {
          bf16x8 bfr = lds_frag(&Ks[(wd * 32 + s * 16 + l15) * 128 + kc * 32 + quad * 8]);
          sacc[s] = mfma_bf16(qf[kk2 * 4 + kc], bfr, sacc[s]);
        }
    }

    // ---- phase 2: online softmax (fp32, no infinities)
#pragma unroll
    for (int s = 0; s < 2; s++)
#pragma unroll
      for (int r = 0; r < 4; r++)
        Sx[wq * 16 + quad * 4 + r][wd * 32 + s * 16 + l15] = sacc[s][r] * SCALE;
    __syncthreads();
    {
      float vals[8];
      float tmax = -3.0e38f;
#pragma unroll
      for (int j = 0; j < 8; j++) {
        float x = Sx[srow][sg * 8 + j];
        x = fminf(fmaxf(x, -1.0e4f), 1.0e4f);  // clamp (also scrubs NaN)
        vals[j] = x;
        tmax = fmaxf(tmax, x);
      }
      tmax = fmaxf(tmax, __shfl_xor(tmax, 1));
      tmax = fmaxf(tmax, __shfl_xor(tmax, 2));
      tmax = fmaxf(tmax, __shfl_xor(tmax, 4));
      const float m_old = m_row[srow];
      const float m_new = fmaxf(m_old, tmax);       // finite always
      const float alpha = __expf(m_old - m_new);    // first tile: exp(-3e38) = 0
      float lsum = 0.f;
      short8 pvec;
#pragma unroll
      for (int j = 0; j < 8; j++) {
        const float p = __expf(vals[j] - m_new);
        lsum += p;
        pvec[j] = (short)f2bf(p);
      }
      lsum += __shfl_xor(lsum, 1);
      lsum += __shfl_xor(lsum, 2);
      lsum += __shfl_xor(lsum, 4);
      *(short8*)(void*)&Pb[srow * 80 + sg * 8] = pvec;
      if (sg == 0) {
        m_row[srow] = m_new;
        l_row[srow] = l_row[srow] * alpha + lsum;
        a_row[srow] = alpha;
      }
    }
    __syncthreads();

    // ---- phase 3: O = O*alpha + P V, 2 d mega-chunks of 256
    float ar[4];
#pragma unroll
    for (int r = 0; r < 4; r++) ar[r] = a_row[wq * 16 + quad * 4 + r];
#pragma unroll
    for (int j = 0; j < 16; j++)
#pragma unroll
      for (int r = 0; r < 4; r++) oacc[j][r] *= ar[r];
    bf16x8 pf[2];  // P as A-operand: A[m=l15][k=key = kc*32 + quad*8 + j]
#pragma unroll
    for (int kc = 0; kc < 2; kc++)
      pf[kc] = lds_frag(&Pb[(wq * 16 + l15) * 80 + kc * 32 + quad * 8]);

    const unsigned short* vbase = Vt + (size_t)b * 4096 + (size_t)kt * 64;
#pragma unroll
    for (int vc = 0; vc < 2; vc++) {
      __syncthreads();  // Vs free
#pragma unroll
      for (int u = 0; u < 8; u++) {
        const int unit = w * 8 + u;  // 0..31, each 8 d x 64 keys
        async_copy16(vbase + (size_t)(vc * 256 + unit * 8 + v_d) * 16384 + v_k,
                     &Vs[unit * 512]);
      }
      __syncthreads();  // Vs ready
#pragma unroll
      for (int jl = 0; jl < 8; jl++) {
        const int j = vc * 8 + jl;
        const int vrow = (jl * 2 + wd) * 16 + l15;  // d row within 256-chunk
#pragma unroll
        for (int kc = 0; kc < 2; kc++) {
          bf16x8 bfr = lds_frag(&Vs[vrow * 64 + kc * 32 + quad * 8]);
          oacc[j] = mfma_bf16(pf[kc], bfr, oacc[j]);
        }
      }
    }
  }

  // ---- epilogue: O / l, f32 store
  __syncthreads();
  float invl[4];
#pragma unroll
  for (int r = 0; r < 4; r++) invl[r] = 1.0f / l_row[wq * 16 + quad * 4 + r];
#pragma unroll
  for (int j = 0; j < 16; j++) {
    const int vcj = j >> 3, jl = j & 7;
    const int ng = vcj * 16 + jl * 2 + wd;  // d-tile index, matches vrow mapping
#pragma unroll
    for (int r = 0; r < 4; r++) {
      const int row = b * 4096 + q0 + wq * 16 + quad * 4 + r;
      O[(size_t)row * 512 + ng * 16 + l15] = oacc[j][r] * invl[r];
    }
  }
}

// ---- launch ---------------------------------------------------------------
extern "C" void kernel_launch(void* const* d_in, const int* in_sizes, int n_in,
                              void* d_out, int out_size, void* d_ws, size_t ws_size,
                              hipStream_t stream) {
  // Inputs are FLOAT32 per the reference (x, w_q, w_k, w_v).
  const float* x   = (const float*)d_in[0];
  const float* wqf = (const float*)d_in[1];
  const float* wkf = (const float*)d_in[2];
  const float* wvf = (const float*)d_in[3];

  // Xb (bf16 X) lives in d_out's low 16 MB: dead before attn overwrites d_out.
  unsigned short* Xb  = (unsigned short*)d_out;        // 16384 x 512 bf16
  unsigned short* Wqb = (unsigned short*)d_ws;         // 512 x 512
  unsigned short* Wkb = Wqb + (size_t)512 * 512;
  unsigned short* Wvb = Wkb + (size_t)512 * 512;
  unsigned short* Q   = Wvb + (size_t)512 * 512;       // 16384 x 512
  unsigned short* K   = Q + (size_t)16384 * 512;       // 16384 x 512
  unsigned short* Vt  = K + (size_t)16384 * 512;       // 512 x 16384 (V^T)

  cvt_f32_bf16<<<dim3(8192), 256, 0, stream>>>(x,   Xb,  2097152);
  cvt_f32_bf16<<<dim3(256),  256, 0, stream>>>(wqf, Wqb, 65536);
  cvt_f32_bf16<<<dim3(256),  256, 0, stream>>>(wkf, Wkb, 65536);
  cvt_f32_bf16<<<dim3(256),  256, 0, stream>>>(wvf, Wvb, 65536);

  gemm_bt<<<dim3(128, 4), 256, 0, stream>>>(Xb, Wqb, Q, 16384, 512);   // Q = X Wq^T
  gemm_bt<<<dim3(128, 4), 256, 0, stream>>>(Xb, Wkb, K, 16384, 512);   // K = X Wk^T
  gemm_bt<<<dim3(4, 128), 256, 0, stream>>>(Wvb, Xb, Vt, 512, 16384);  // V^T = Wv X^T
  attn_kernel<<<dim3(512), 256, 0, stream>>>(Q, K, Vt, (float*)d_out);
}

// Round 4
// 436.736 us; speedup vs baseline: 1.4698x; 1.4698x over previous
//
#include <hip/hip_runtime.h>
#include <math.h>

// ---- types ----------------------------------------------------------------
typedef __attribute__((ext_vector_type(8))) __bf16 bf16x8;   // MFMA A/B frag (4 VGPR)
typedef __attribute__((ext_vector_type(8))) short  short8;   // raw 16B store
typedef __attribute__((ext_vector_type(4))) unsigned short ushort4v;
typedef __attribute__((ext_vector_type(4))) float  floatx4;  // MFMA C/D frag

typedef __attribute__((address_space(1))) unsigned int as1_u32;
typedef __attribute__((address_space(3))) unsigned int as3_u32;

// async global->LDS, 16B per lane; LDS dest = wave-uniform base + lane*16B
__device__ __forceinline__ void async_copy16(const void* g, void* l) {
  __builtin_amdgcn_global_load_lds((const as1_u32*)g, (as3_u32*)l, 16, 0, 0);
}

__device__ __forceinline__ unsigned short f2bf(float f) {  // RNE float->bf16 bits
  union { float f; unsigned u; } v; v.f = f;
  unsigned r = v.u + 0x7fffu + ((v.u >> 16) & 1u);
  return (unsigned short)(r >> 16);
}

__device__ __forceinline__ floatx4 mfma_bf16(bf16x8 a, bf16x8 b, floatx4 c) {
  return __builtin_amdgcn_mfma_f32_16x16x32_bf16(a, b, c, 0, 0, 0);
}

__device__ __forceinline__ bf16x8 lds_frag(const unsigned short* p) {
  return *(const bf16x8*)(const void*)p;  // ds_read_b128, 16B aligned by construction
}

// XOR swizzle: LDS[row][chunk ^ (row & mask)] holds logical [row][chunk].
// Copies stay dense (global_load_lds-compatible): lane's SOURCE chunk is
// XORed instead. Makes frag reads (stride 64/128 elem) conflict-free.

// ---- f32 -> bf16 convert (RNE), vectorized 4/thread -----------------------
__global__ __launch_bounds__(256)
void cvt_f32_bf16(const float* __restrict__ src, unsigned short* __restrict__ dst, int n4) {
  const int i = blockIdx.x * 256 + threadIdx.x;
  if (i < n4) {
    const float4 v = ((const float4*)src)[i];
    ushort4v o;
    o.x = f2bf(v.x); o.y = f2bf(v.y); o.z = f2bf(v.z); o.w = f2bf(v.w);
    *(ushort4v*)(void*)(dst + (size_t)i * 4) = o;
  }
}

// ---- C = A(MxK) * B(NxK)^T, K=512, bf16 in/out, fp32 accumulate -----------
// m97 structure + XOR swizzle (rows 64 elem = 8 chunks of 16B; mask 7).
__global__ __launch_bounds__(256, 2)
void gemm_bt(const unsigned short* __restrict__ A,
             const unsigned short* __restrict__ B,
             unsigned short* __restrict__ C, int M, int N) {
  __shared__ unsigned short As[128 * 64];
  __shared__ unsigned short Bs[128 * 64];
  const int tid = threadIdx.x;
  const int w = tid >> 6, lane = tid & 63;
  const int quad = lane >> 4, l15 = lane & 15;
  const int wm = w >> 1, wn = w & 1;
  const int m0 = blockIdx.x * 128, n0 = blockIdx.y * 128;
  const int row_l = lane >> 3;          // 0..7 row within copy unit
  const int chk   = lane & 7;           // 16B chunk within row
  const int s_chk = chk ^ row_l;        // swizzled SOURCE chunk (unit*8 & 7 == 0)

  floatx4 acc[16];
#pragma unroll
  for (int i = 0; i < 16; i++) acc[i] = (floatx4){0.f, 0.f, 0.f, 0.f};

  for (int kt = 0; kt < 8; kt++) {
    __syncthreads();
#pragma unroll
    for (int i = 0; i < 4; i++) {
      const int c = w * 4 + i;
      const int row = c * 8 + row_l;
      async_copy16(A + (size_t)(m0 + row) * 512 + kt * 64 + s_chk * 8, &As[c * 512]);
      async_copy16(B + (size_t)(n0 + row) * 512 + kt * 64 + s_chk * 8, &Bs[c * 512]);
    }
    __syncthreads();
#pragma unroll
    for (int kc = 0; kc < 2; kc++) {
      bf16x8 af[4], bfv[4];
#pragma unroll
      for (int i = 0; i < 4; i++) {
        const int pc = ((kc * 4 + quad) ^ (l15 & 7)) * 8;  // swizzled chunk offset
        af[i]  = lds_frag(&As[(wm * 64 + i * 16 + l15) * 64 + pc]);
        bfv[i] = lds_frag(&Bs[(wn * 64 + i * 16 + l15) * 64 + pc]);
      }
#pragma unroll
      for (int mi = 0; mi < 4; mi++)
#pragma unroll
        for (int ni = 0; ni < 4; ni++)
          acc[mi * 4 + ni] = mfma_bf16(af[mi], bfv[ni], acc[mi * 4 + ni]);
    }
  }
  // C/D layout: col = lane&15, row = quad*4 + r (m89-verified)
#pragma unroll
  for (int mi = 0; mi < 4; mi++)
#pragma unroll
    for (int ni = 0; ni < 4; ni++)
#pragma unroll
      for (int r = 0; r < 4; r++) {
        const int row = m0 + wm * 64 + mi * 16 + quad * 4 + r;
        const int col = n0 + wn * 64 + ni * 16 + l15;
        C[(size_t)row * N + col] = f2bf(acc[mi * 4 + ni][r]);
      }
}

// ---- fused attention: full (non-causal) softmax over 4096 keys ------------
// Round-3 structure + conflict-free LDS (XOR swizzle Ks/Vs, padded Sx/Pb).
#define SCALE 0.044194173824159216f  // 1/sqrt(512)

__global__ __launch_bounds__(256, 2)
void attn_kernel(const unsigned short* __restrict__ Qg,
                 const unsigned short* __restrict__ Kg,
                 const unsigned short* __restrict__ Vt,   // [512][16384] = V^T
                 float* __restrict__ O) {                 // f32 output
  __shared__ unsigned short Ks[64 * 128];   // 16 KB: 64 keys x 128 feats (swizzled, mask 15)
  __shared__ unsigned short Vs[256 * 64];   // 32 KB: 256 d x 64 keys (swizzled, mask 7)
  __shared__ float Sx[32][65];              // padded: stride 65 words -> ~2-way max
  __shared__ unsigned short Pb[32 * 72];    // stride 72 elem = 36 words == 4 mod 32
  __shared__ float m_row[32], l_row[32], a_row[32];

  const int tid = threadIdx.x;
  const int w = tid >> 6, lane = tid & 63;
  const int quad = lane >> 4, l15 = lane & 15;
  const int wq = w >> 1, wd = w & 1;

  const int g = blockIdx.x;
  const int b = (g >> 1) & 3;
  const int qt = ((g >> 3) << 1) | (g & 1);
  const int q0 = qt * 32;

  if (tid < 32) { m_row[tid] = -3.0e38f; l_row[tid] = 0.f; }

  // Q A-fragments in registers: A[m=l15][k = i*32 + quad*8 + j]
  bf16x8 qf[16];
  {
    const unsigned short* qrow = Qg + (size_t)(b * 4096 + q0 + wq * 16 + l15) * 512;
#pragma unroll
    for (int i = 0; i < 16; i++)
      qf[i] = *(const bf16x8*)(const void*)(qrow + i * 32 + quad * 8);
  }

  floatx4 oacc[16];
#pragma unroll
  for (int i = 0; i < 16; i++) oacc[i] = (floatx4){0.f, 0.f, 0.f, 0.f};

  const int srow = tid >> 3, sg = tid & 7;   // softmax: 8 threads per q-row
  const int k_key = lane >> 4;               // K-copy: row within 4-key unit
  const int k_chk = lane & 15;               // 16B chunk (16 per 256B row)
  const int v_d = lane >> 3;                 // V-copy: row within 8-d unit
  const int v_chk = lane & 7;                // 16B chunk (8 per 128B row)
  const int v_schk = v_chk ^ v_d;            // swizzled source chunk (unit*8 & 7 == 0)

  for (int kt = 0; kt < 64; kt++) {
    const unsigned short* kbase = Kg + (size_t)(b * 4096 + kt * 64) * 512;

    // ---- phase 1: S(32q x 64keys) = Q K^T, 4 feature mega-chunks of 128
    floatx4 sacc[2];
    sacc[0] = (floatx4){0.f, 0.f, 0.f, 0.f};
    sacc[1] = (floatx4){0.f, 0.f, 0.f, 0.f};
#pragma unroll
    for (int kk2 = 0; kk2 < 4; kk2++) {
      __syncthreads();
#pragma unroll
      for (int u = 0; u < 4; u++) {
        const int unit = w * 4 + u;                    // 0..15: 4 keys x 128 feats
        const int row = unit * 4 + k_key;              // key row in tile
        const int schk = k_chk ^ (row & 15);           // swizzled source chunk
        async_copy16(kbase + (size_t)row * 512 + kk2 * 128 + schk * 8,
                     &Ks[unit * 512]);
      }
      __syncthreads();
#pragma unroll
      for (int kc = 0; kc < 4; kc++)
#pragma unroll
        for (int s = 0; s < 2; s++) {
          const int krow = wd * 32 + s * 16 + l15;     // krow & 15 == l15
          bf16x8 bfr = lds_frag(&Ks[krow * 128 + (((kc * 4 + quad) ^ l15) * 8)]);
          sacc[s] = mfma_bf16(qf[kk2 * 4 + kc], bfr, sacc[s]);
        }
    }

    // ---- phase 2: online softmax (fp32, no infinities)
#pragma unroll
    for (int s = 0; s < 2; s++)
#pragma unroll
      for (int r = 0; r < 4; r++)
        Sx[wq * 16 + quad * 4 + r][wd * 32 + s * 16 + l15] = sacc[s][r] * SCALE;
    __syncthreads();
    {
      float vals[8];
      float tmax = -3.0e38f;
#pragma unroll
      for (int j = 0; j < 8; j++) {
        float x = Sx[srow][sg * 8 + j];
        x = fminf(fmaxf(x, -1.0e4f), 1.0e4f);
        vals[j] = x;
        tmax = fmaxf(tmax, x);
      }
      tmax = fmaxf(tmax, __shfl_xor(tmax, 1));
      tmax = fmaxf(tmax, __shfl_xor(tmax, 2));
      tmax = fmaxf(tmax, __shfl_xor(tmax, 4));
      const float m_old = m_row[srow];
      const float m_new = fmaxf(m_old, tmax);
      const float alpha = __expf(m_old - m_new);
      float lsum = 0.f;
      short8 pvec;
#pragma unroll
      for (int j = 0; j < 8; j++) {
        const float p = __expf(vals[j] - m_new);
        lsum += p;
        pvec[j] = (short)f2bf(p);
      }
      lsum += __shfl_xor(lsum, 1);
      lsum += __shfl_xor(lsum, 2);
      lsum += __shfl_xor(lsum, 4);
      *(short8*)(void*)&Pb[srow * 72 + sg * 8] = pvec;
      if (sg == 0) {
        m_row[srow] = m_new;
        l_row[srow] = l_row[srow] * alpha + lsum;
        a_row[srow] = alpha;
      }
    }
    __syncthreads();

    // ---- phase 3: O = O*alpha + P V, 2 d mega-chunks of 256
    float ar[4];
#pragma unroll
    for (int r = 0; r < 4; r++) ar[r] = a_row[wq * 16 + quad * 4 + r];
#pragma unroll
    for (int j = 0; j < 16; j++)
#pragma unroll
      for (int r = 0; r < 4; r++) oacc[j][r] *= ar[r];
    bf16x8 pf[2];  // P as A-operand
#pragma unroll
    for (int kc = 0; kc < 2; kc++)
      pf[kc] = lds_frag(&Pb[(wq * 16 + l15) * 72 + kc * 32 + quad * 8]);

    const unsigned short* vbase = Vt + (size_t)b * 4096 + (size_t)kt * 64;
#pragma unroll
    for (int vc = 0; vc < 2; vc++) {
      __syncthreads();
#pragma unroll
      for (int u = 0; u < 8; u++) {
        const int unit = w * 8 + u;  // 0..31: 8 d-rows x 64 keys
        async_copy16(vbase + (size_t)(vc * 256 + unit * 8 + v_d) * 16384 + v_schk * 8,
                     &Vs[unit * 512]);
      }
      __syncthreads();
#pragma unroll
      for (int jl = 0; jl < 8; jl++) {
        const int j = vc * 8 + jl;
        const int vrow = (jl * 2 + wd) * 16 + l15;     // vrow & 7 == l15 & 7
#pragma unroll
        for (int kc = 0; kc < 2; kc++) {
          bf16x8 bfr = lds_frag(&Vs[vrow * 64 + (((kc * 4 + quad) ^ (l15 & 7)) * 8)]);
          oacc[j] = mfma_bf16(pf[kc], bfr, oacc[j]);
        }
      }
    }
  }

  // ---- epilogue: O / l, f32 store
  __syncthreads();
  float invl[4];
#pragma unroll
  for (int r = 0; r < 4; r++) invl[r] = 1.0f / l_row[wq * 16 + quad * 4 + r];
#pragma unroll
  for (int j = 0; j < 16; j++) {
    const int vcj = j >> 3, jl = j & 7;
    const int ng = vcj * 16 + jl * 2 + wd;
#pragma unroll
    for (int r = 0; r < 4; r++) {
      const int row = b * 4096 + q0 + wq * 16 + quad * 4 + r;
      O[(size_t)row * 512 + ng * 16 + l15] = oacc[j][r] * invl[r];
    }
  }
}

// ---- launch ---------------------------------------------------------------
extern "C" void kernel_launch(void* const* d_in, const int* in_sizes, int n_in,
                              void* d_out, int out_size, void* d_ws, size_t ws_size,
                              hipStream_t stream) {
  const float* x   = (const float*)d_in[0];
  const float* wqf = (const float*)d_in[1];
  const float* wkf = (const float*)d_in[2];
  const float* wvf = (const float*)d_in[3];

  unsigned short* Xb  = (unsigned short*)d_out;        // 16384 x 512 bf16 (dead before attn)
  unsigned short* Wqb = (unsigned short*)d_ws;         // 512 x 512
  unsigned short* Wkb = Wqb + (size_t)512 * 512;
  unsigned short* Wvb = Wkb + (size_t)512 * 512;
  unsigned short* Q   = Wvb + (size_t)512 * 512;       // 16384 x 512
  unsigned short* K   = Q + (size_t)16384 * 512;       // 16384 x 512
  unsigned short* Vt  = K + (size_t)16384 * 512;       // 512 x 16384 (V^T)

  cvt_f32_bf16<<<dim3(8192), 256, 0, stream>>>(x,   Xb,  2097152);
  cvt_f32_bf16<<<dim3(256),  256, 0, stream>>>(wqf, Wqb, 65536);
  cvt_f32_bf16<<<dim3(256),  256, 0, stream>>>(wkf, Wkb, 65536);
  cvt_f32_bf16<<<dim3(256),  256, 0, stream>>>(wvf, Wvb, 65536);

  gemm_bt<<<dim3(128, 4), 256, 0, stream>>>(Xb, Wqb, Q, 16384, 512);   // Q = X Wq^T
  gemm_bt<<<dim3(128, 4), 256, 0, stream>>>(Xb, Wkb, K, 16384, 512);   // K = X Wk^T
  gemm_bt<<<dim3(4, 128), 256, 0, stream>>>(Wvb, Xb, Vt, 512, 16384);  // V^T = Wv X^T
  attn_kernel<<<dim3(512), 256, 0, stream>>>(Q, K, Vt, (float*)d_out);
}

// Round 5
// 433.814 us; speedup vs baseline: 1.4797x; 1.0067x over previous
//
#include <hip/hip_runtime.h>
#include <math.h>

// ---- types ----------------------------------------------------------------
typedef __attribute__((ext_vector_type(8))) __bf16 bf16x8;   // MFMA A/B frag (4 VGPR)
typedef __attribute__((ext_vector_type(8))) short  short8;   // raw 16B store
typedef __attribute__((ext_vector_type(4))) unsigned short ushort4v;
typedef __attribute__((ext_vector_type(4))) float  floatx4;  // MFMA C/D frag

typedef __attribute__((address_space(1))) unsigned int as1_u32;
typedef __attribute__((address_space(3))) unsigned int as3_u32;

// async global->LDS (still used by the GEMM; attn now uses reg-prefetch)
__device__ __forceinline__ void async_copy16(const void* g, void* l) {
  __builtin_amdgcn_global_load_lds((const as1_u32*)g, (as3_u32*)l, 16, 0, 0);
}

__device__ __forceinline__ unsigned short f2bf(float f) {  // RNE float->bf16 bits
  union { float f; unsigned u; } v; v.f = f;
  unsigned r = v.u + 0x7fffu + ((v.u >> 16) & 1u);
  return (unsigned short)(r >> 16);
}

__device__ __forceinline__ floatx4 mfma_bf16(bf16x8 a, bf16x8 b, floatx4 c) {
  return __builtin_amdgcn_mfma_f32_16x16x32_bf16(a, b, c, 0, 0, 0);
}

__device__ __forceinline__ bf16x8 lds_frag(const unsigned short* p) {
  return *(const bf16x8*)(const void*)p;  // ds_read_b128
}

// ---- prep: all four f32->bf16 conversions in ONE launch --------------------
// Segments (float4 units): x 2097152 | wq 65536 | wk 65536 | wv 65536.
// All boundaries are multiples of 256 -> no intra-block divergence.
__global__ __launch_bounds__(256)
void prep(const float* __restrict__ x,  const float* __restrict__ wq,
          const float* __restrict__ wk, const float* __restrict__ wv,
          unsigned short* __restrict__ Xb, unsigned short* __restrict__ Wqb,
          unsigned short* __restrict__ Wkb, unsigned short* __restrict__ Wvb) {
  const int i = blockIdx.x * 256 + threadIdx.x;
  const float* s; unsigned short* d; int off;
  if (i < 2097152)             { s = x;  d = Xb;  off = i; }
  else if (i < 2097152+65536)  { s = wq; d = Wqb; off = i - 2097152; }
  else if (i < 2097152+131072) { s = wk; d = Wkb; off = i - (2097152+65536); }
  else                         { s = wv; d = Wvb; off = i - (2097152+131072); }
  const float4 v = ((const float4*)s)[off];
  ushort4v o;
  o.x = f2bf(v.x); o.y = f2bf(v.y); o.z = f2bf(v.z); o.w = f2bf(v.w);
  *(ushort4v*)(void*)(d + (size_t)off * 4) = o;
}

// ---- fused QKV GEMM: three C = A(Mx512)·B(Nx512)^T problems, one launch ----
// m97 structure + XOR swizzle (round-4 verified). Block-uniform dispatch.
__global__ __launch_bounds__(256, 2)
void gemm_qkv(const unsigned short* __restrict__ Xb,
              const unsigned short* __restrict__ Wqb,
              const unsigned short* __restrict__ Wkb,
              const unsigned short* __restrict__ Wvb,
              unsigned short* __restrict__ Q,
              unsigned short* __restrict__ K,
              unsigned short* __restrict__ Vt) {
  const int gid = blockIdx.x;
  const unsigned short *A, *B; unsigned short* C;
  int m0, n0, N;
  if (gid < 512) {                        // Q = Xb · Wq^T
    A = Xb; B = Wqb; C = Q; N = 512;
    m0 = (gid & 127) * 128; n0 = (gid >> 7) * 128;
  } else if (gid < 1024) {                // K = Xb · Wk^T
    A = Xb; B = Wkb; C = K; N = 512;
    m0 = ((gid - 512) & 127) * 128; n0 = ((gid - 512) >> 7) * 128;
  } else {                                // V^T = Wv · Xb^T  (M=512, N=16384)
    A = Wvb; B = Xb; C = Vt; N = 16384;
    m0 = ((gid - 1024) & 3) * 128; n0 = ((gid - 1024) >> 2) * 128;
  }

  __shared__ unsigned short As[128 * 64];
  __shared__ unsigned short Bs[128 * 64];
  const int tid = threadIdx.x;
  const int w = tid >> 6, lane = tid & 63;
  const int quad = lane >> 4, l15 = lane & 15;
  const int wm = w >> 1, wn = w & 1;
  const int row_l = lane >> 3;
  const int chk   = lane & 7;
  const int s_chk = chk ^ row_l;          // swizzled SOURCE chunk

  floatx4 acc[16];
#pragma unroll
  for (int i = 0; i < 16; i++) acc[i] = (floatx4){0.f, 0.f, 0.f, 0.f};

  for (int kt = 0; kt < 8; kt++) {
    __syncthreads();
#pragma unroll
    for (int i = 0; i < 4; i++) {
      const int c = w * 4 + i;
      const int row = c * 8 + row_l;
      async_copy16(A + (size_t)(m0 + row) * 512 + kt * 64 + s_chk * 8, &As[c * 512]);
      async_copy16(B + (size_t)(n0 + row) * 512 + kt * 64 + s_chk * 8, &Bs[c * 512]);
    }
    __syncthreads();
#pragma unroll
    for (int kc = 0; kc < 2; kc++) {
      bf16x8 af[4], bfv[4];
#pragma unroll
      for (int i = 0; i < 4; i++) {
        const int pc = ((kc * 4 + quad) ^ (l15 & 7)) * 8;
        af[i]  = lds_frag(&As[(wm * 64 + i * 16 + l15) * 64 + pc]);
        bfv[i] = lds_frag(&Bs[(wn * 64 + i * 16 + l15) * 64 + pc]);
      }
#pragma unroll
      for (int mi = 0; mi < 4; mi++)
#pragma unroll
        for (int ni = 0; ni < 4; ni++)
          acc[mi * 4 + ni] = mfma_bf16(af[mi], bfv[ni], acc[mi * 4 + ni]);
    }
  }
#pragma unroll
  for (int mi = 0; mi < 4; mi++)
#pragma unroll
    for (int ni = 0; ni < 4; ni++)
#pragma unroll
      for (int r = 0; r < 4; r++) {
        const int row = m0 + wm * 64 + mi * 16 + quad * 4 + r;
        const int col = n0 + wn * 64 + ni * 16 + l15;
        C[(size_t)row * N + col] = f2bf(acc[mi * 4 + ni][r]);
      }
}

// ---- fused attention with register-prefetch pipelined staging --------------
// Same LDS layout/swizzle as round 4 (verified). Transport changed:
// global->VGPR loads issued ONE CHUNK AHEAD, ds_write at consume time.
// Compiler emits precise s_waitcnt vmcnt(N) before each ds_write, so load
// latency overlaps the previous chunk's MFMA instead of draining at barriers.
#define SCALE 0.044194173824159216f  // 1/sqrt(512)

__global__ __launch_bounds__(256, 2)
void attn_kernel(const unsigned short* __restrict__ Qg,
                 const unsigned short* __restrict__ Kg,
                 const unsigned short* __restrict__ Vt,   // [512][16384] = V^T
                 float* __restrict__ O) {                 // f32 output
  __shared__ unsigned short Ks[64 * 128];   // 16 KB: 64 keys x 128 feats (swizzled)
  __shared__ unsigned short Vs[256 * 64];   // 32 KB: 256 d x 64 keys (swizzled)
  __shared__ float Sx[32][65];
  __shared__ unsigned short Pb[32 * 72];
  __shared__ float m_row[32], l_row[32], a_row[32];

  const int tid = threadIdx.x;
  const int w = tid >> 6, lane = tid & 63;
  const int quad = lane >> 4, l15 = lane & 15;
  const int wq = w >> 1, wd = w & 1;

  const int g = blockIdx.x;
  const int b = (g >> 1) & 3;
  const int qt = ((g >> 3) << 1) | (g & 1);
  const int q0 = qt * 32;

  if (tid < 32) { m_row[tid] = -3.0e38f; l_row[tid] = 0.f; }

  // Q A-fragments in registers
  bf16x8 qf[16];
  {
    const unsigned short* qrow = Qg + (size_t)(b * 4096 + q0 + wq * 16 + l15) * 512;
#pragma unroll
    for (int i = 0; i < 16; i++)
      qf[i] = *(const bf16x8*)(const void*)(qrow + i * 32 + quad * 8);
  }

  floatx4 oacc[16];
#pragma unroll
  for (int i = 0; i < 16; i++) oacc[i] = (floatx4){0.f, 0.f, 0.f, 0.f};

  const int srow = tid >> 3, sg = tid & 7;
  const int k_key = lane >> 4, k_chk = lane & 15;  // K copy: 4 keys x 16 chunks
  const int v_d = lane >> 3;                       // V copy: 8 d-rows x 8 chunks
  const int v_schk = (lane & 7) ^ v_d;

  const unsigned short* kb0 = Kg + (size_t)b * 4096 * 512;
  const unsigned short* vb0 = Vt + (size_t)b * 4096;

  bf16x8 kr[4], vr[8];  // prefetch registers

  // source addresses identical to round 4's async_copy16 sources
  auto load_K = [&](int kt_, int kk2_) {
#pragma unroll
    for (int u = 0; u < 4; u++) {
      const int row = (w * 4 + u) * 4 + k_key;
      kr[u] = *(const bf16x8*)(const void*)(
          kb0 + ((size_t)kt_ * 64 + row) * 512 + kk2_ * 128 + (k_chk ^ (row & 15)) * 8);
    }
  };
  auto load_V = [&](int kt_, int vc_) {
#pragma unroll
    for (int u = 0; u < 8; u++) {
      const int unit = w * 8 + u;
      vr[u] = *(const bf16x8*)(const void*)(
          vb0 + (size_t)kt_ * 64 + (size_t)(vc_ * 256 + unit * 8 + v_d) * 16384 + v_schk * 8);
    }
  };

  load_K(0, 0);  // prologue: first chunk in flight

  for (int kt = 0; kt < 64; kt++) {
    // ---- phase 1: S(32q x 64keys) = Q K^T over 4 feature chunks of 128
    floatx4 sacc[2];
    sacc[0] = (floatx4){0.f, 0.f, 0.f, 0.f};
    sacc[1] = (floatx4){0.f, 0.f, 0.f, 0.f};
#pragma unroll
    for (int kk2 = 0; kk2 < 4; kk2++) {
      __syncthreads();  // all waves done READING Ks (prev chunk)
#pragma unroll
      for (int u = 0; u < 4; u++)  // ds_write chunk kk2 (vmcnt waits precisely here)
        *(bf16x8*)(void*)&Ks[(w * 4 + u) * 512 + lane * 8] = kr[u];
      if (kk2 < 3) load_K(kt, kk2 + 1);  // prefetch next chunk
      else         load_V(kt, 0);        // prefetch V chunk 0 (covered by softmax)
      __syncthreads();  // Ks visible to all waves
#pragma unroll
      for (int kc = 0; kc < 4; kc++)
#pragma unroll
        for (int s = 0; s < 2; s++) {
          const int krow = wd * 32 + s * 16 + l15;
          bf16x8 bfr = lds_frag(&Ks[krow * 128 + (((kc * 4 + quad) ^ l15) * 8)]);
          sacc[s] = mfma_bf16(qf[kk2 * 4 + kc], bfr, sacc[s]);
        }
    }

    // ---- phase 2: online softmax (fp32)
#pragma unroll
    for (int s = 0; s < 2; s++)
#pragma unroll
      for (int r = 0; r < 4; r++)
        Sx[wq * 16 + quad * 4 + r][wd * 32 + s * 16 + l15] = sacc[s][r] * SCALE;
    __syncthreads();
    {
      float vals[8];
      float tmax = -3.0e38f;
#pragma unroll
      for (int j = 0; j < 8; j++) {
        float xv = Sx[srow][sg * 8 + j];
        xv = fminf(fmaxf(xv, -1.0e4f), 1.0e4f);
        vals[j] = xv;
        tmax = fmaxf(tmax, xv);
      }
      tmax = fmaxf(tmax, __shfl_xor(tmax, 1));
      tmax = fmaxf(tmax, __shfl_xor(tmax, 2));
      tmax = fmaxf(tmax, __shfl_xor(tmax, 4));
      const float m_old = m_row[srow];
      const float m_new = fmaxf(m_old, tmax);
      const float alpha = __expf(m_old - m_new);
      float lsum = 0.f;
      short8 pvec;
#pragma unroll
      for (int j = 0; j < 8; j++) {
        const float p = __expf(vals[j] - m_new);
        lsum += p;
        pvec[j] = (short)f2bf(p);
      }
      lsum += __shfl_xor(lsum, 1);
      lsum += __shfl_xor(lsum, 2);
      lsum += __shfl_xor(lsum, 4);
      *(short8*)(void*)&Pb[srow * 72 + sg * 8] = pvec;
      if (sg == 0) {
        m_row[srow] = m_new;
        l_row[srow] = l_row[srow] * alpha + lsum;
        a_row[srow] = alpha;
      }
    }
    __syncthreads();

    // ---- phase 3: O = O*alpha + P V over 2 d chunks of 256
    float ar[4];
#pragma unroll
    for (int r = 0; r < 4; r++) ar[r] = a_row[wq * 16 + quad * 4 + r];
#pragma unroll
    for (int j = 0; j < 16; j++)
#pragma unroll
      for (int r = 0; r < 4; r++) oacc[j][r] *= ar[r];
    bf16x8 pf[2];
#pragma unroll
    for (int kc = 0; kc < 2; kc++)
      pf[kc] = lds_frag(&Pb[(wq * 16 + l15) * 72 + kc * 32 + quad * 8]);

#pragma unroll
    for (int vc = 0; vc < 2; vc++) {
      __syncthreads();  // all waves done READING Vs (prev chunk)
#pragma unroll
      for (int u = 0; u < 8; u++)
        *(bf16x8*)(void*)&Vs[(w * 8 + u) * 512 + lane * 8] = vr[u];
      if (vc == 0) load_V(kt, 1);
      else         load_K((kt + 1) & 63, 0);  // next kt's first K chunk (wraps; dead at kt=63)
      __syncthreads();  // Vs visible
#pragma unroll
      for (int jl = 0; jl < 8; jl++) {
        const int j = vc * 8 + jl;
        const int vrow = (jl * 2 + wd) * 16 + l15;
#pragma unroll
        for (int kc = 0; kc < 2; kc++) {
          bf16x8 bfr = lds_frag(&Vs[vrow * 64 + (((kc * 4 + quad) ^ (l15 & 7)) * 8)]);
          oacc[j] = mfma_bf16(pf[kc], bfr, oacc[j]);
        }
      }
    }
  }

  // ---- epilogue: O / l, f32 store
  __syncthreads();
  float invl[4];
#pragma unroll
  for (int r = 0; r < 4; r++) invl[r] = 1.0f / l_row[wq * 16 + quad * 4 + r];
#pragma unroll
  for (int j = 0; j < 16; j++) {
    const int vcj = j >> 3, jl = j & 7;
    const int ng = vcj * 16 + jl * 2 + wd;
#pragma unroll
    for (int r = 0; r < 4; r++) {
      const int row = b * 4096 + q0 + wq * 16 + quad * 4 + r;
      O[(size_t)row * 512 + ng * 16 + l15] = oacc[j][r] * invl[r];
    }
  }
}

// ---- launch ---------------------------------------------------------------
extern "C" void kernel_launch(void* const* d_in, const int* in_sizes, int n_in,
                              void* d_out, int out_size, void* d_ws, size_t ws_size,
                              hipStream_t stream) {
  const float* x   = (const float*)d_in[0];
  const float* wqf = (const float*)d_in[1];
  const float* wkf = (const float*)d_in[2];
  const float* wvf = (const float*)d_in[3];

  unsigned short* Xb  = (unsigned short*)d_out;        // 16384 x 512 bf16 (dead before attn)
  unsigned short* Wqb = (unsigned short*)d_ws;         // 512 x 512
  unsigned short* Wkb = Wqb + (size_t)512 * 512;
  unsigned short* Wvb = Wkb + (size_t)512 * 512;
  unsigned short* Q   = Wvb + (size_t)512 * 512;       // 16384 x 512
  unsigned short* K   = Q + (size_t)16384 * 512;       // 16384 x 512
  unsigned short* Vt  = K + (size_t)16384 * 512;       // 512 x 16384 (V^T)

  prep<<<dim3(8960), 256, 0, stream>>>(x, wqf, wkf, wvf, Xb, Wqb, Wkb, Wvb);
  gemm_qkv<<<dim3(1536), 256, 0, stream>>>(Xb, Wqb, Wkb, Wvb, Q, K, Vt);
  attn_kernel<<<dim3(512), 256, 0, stream>>>(Q, K, Vt, (float*)d_out);
}